// Round 1
// baseline (342.275 us; speedup 1.0000x reference)
//
#include <hip/hip_runtime.h>
#include <stdint.h>

// SmallMLP: x[65536,784] @ tern(w1[320,784])^T + b1 -> tern -> @ tern(w2[10,320])^T + b2 -> log_softmax
// Layer-1 via two-term bf16-split MFMA (16x16x32), fully fused epilogue (layer 2 + log_softmax).

#define TERN_TH 0.001f

using bf16x8 = __attribute__((ext_vector_type(8))) short;   // 8 bf16 = 4 VGPR
using f32x4  = __attribute__((ext_vector_type(4))) float;   // 4 fp32 acc

__device__ __forceinline__ unsigned short f2bf(float f) {
    unsigned u = __float_as_uint(f);
    u = (u + 0x7FFFu + ((u >> 16) & 1u)) >> 16;   // RNE
    return (unsigned short)u;
}
__device__ __forceinline__ float bf2f(unsigned short h) {
    return __uint_as_float(((unsigned)h) << 16);
}
__device__ __forceinline__ float ternf(float w) {
    return (w > TERN_TH) ? 1.0f : ((w < -TERN_TH) ? -1.0f : 0.0f);
}

// ---------------- prep: ternarize w1 -> bf16, tiled [25 chunks][320 rows][40 k] (k pad 32->40 for LDS banking)
#define Q1T_ELEMS (25 * 320 * 40)
__global__ void prep_q1(const float* __restrict__ w1, unsigned short* __restrict__ q1t) {
    int idx = blockIdx.x * 256 + threadIdx.x;
    if (idx >= Q1T_ELEMS) return;
    int c  = idx / (320 * 40);
    int r  = idx % (320 * 40);
    int j  = r / 40;
    int kk = r % 40;
    int k  = c * 32 + kk;
    float v = 0.0f;
    if (kk < 32 && k < 784) v = ternf(w1[j * 784 + k]);
    q1t[idx] = f2bf(v);
}

// ---------------- LDS layout (bytes)
#define LDS_AHI 0                 // [128][40] bf16 = 10240
#define LDS_ALO 10240             // [128][40] bf16 = 10240
#define LDS_B   20480             // [320][40] bf16 = 25600  -> ends 46080
#define LDS_H   0                 // epilogue: [64][328] bf16 = 41984 (overlaps A/B, dead by then)
#define LDS_Q2  46080             // [16][328] bf16 = 10496  -> total 56576
#define LDS_TOTAL 56576

__global__ __launch_bounds__(256, 2) void mlp_main(
    const float* __restrict__ x, const unsigned short* __restrict__ q1t,
    const float* __restrict__ b1, const float* __restrict__ w2,
    const float* __restrict__ b2, float* __restrict__ out) {

    __shared__ __attribute__((aligned(16))) unsigned char smem[LDS_TOTAL];
    unsigned short* sm16 = (unsigned short*)smem;

    const int tid  = threadIdx.x;
    const int lane = tid & 63;
    const int wave = tid >> 6;     // 4 waves
    const int quad = lane >> 4;
    const int l15  = lane & 15;
    const int wm   = wave >> 1;    // 0..1 : row half (64 rows)
    const int wn   = wave & 1;     // 0..1 : col half (160 cols)
    const int blk  = blockIdx.x;   // 512 blocks * 128 rows

    f32x4 acc[4][10];
#pragma unroll
    for (int mt = 0; mt < 4; ++mt)
#pragma unroll
        for (int nt = 0; nt < 10; ++nt) {
            f32x4 z = {0.f, 0.f, 0.f, 0.f};
            acc[mt][nt] = z;
        }

    // staging coords: 2 threads per row, 16 floats each
    const int srow  = tid >> 1;    // 0..127
    const int shalf = tid & 1;     // 0..1
    const float* xrow = x + (size_t)(blk * 128 + srow) * 784 + shalf * 16;

    for (int c = 0; c < 25; ++c) {
        __syncthreads();
        // ---- stage A: x tile 128x32 fp32 -> hi/lo bf16 split
        {
            float v[16];
            {
                float4 a0, a1, a2, a3;
                if (c < 24 || shalf == 0) {
                    const float4* s4 = (const float4*)(xrow + c * 32);
                    a0 = s4[0]; a1 = s4[1]; a2 = s4[2]; a3 = s4[3];
                } else {
                    a0.x = a0.y = a0.z = a0.w = 0.f;  // K tail 784..799 -> zeros
                    a1 = a0; a2 = a0; a3 = a0;
                }
                v[0]=a0.x; v[1]=a0.y; v[2]=a0.z;  v[3]=a0.w;
                v[4]=a1.x; v[5]=a1.y; v[6]=a1.z;  v[7]=a1.w;
                v[8]=a2.x; v[9]=a2.y; v[10]=a2.z; v[11]=a2.w;
                v[12]=a3.x; v[13]=a3.y; v[14]=a3.z; v[15]=a3.w;
            }
            unsigned hw[8], lw[8];
#pragma unroll
            for (int i = 0; i < 8; ++i) {
                unsigned short h0 = f2bf(v[2 * i]);
                unsigned short h1 = f2bf(v[2 * i + 1]);
                unsigned short g0 = f2bf(v[2 * i]     - bf2f(h0));
                unsigned short g1 = f2bf(v[2 * i + 1] - bf2f(h1));
                hw[i] = (unsigned)h0 | ((unsigned)h1 << 16);
                lw[i] = (unsigned)g0 | ((unsigned)g1 << 16);
            }
            uint4* dh = (uint4*)(smem + LDS_AHI + srow * 80 + shalf * 32);
            dh[0] = make_uint4(hw[0], hw[1], hw[2], hw[3]);
            dh[1] = make_uint4(hw[4], hw[5], hw[6], hw[7]);
            uint4* dl = (uint4*)(smem + LDS_ALO + srow * 80 + shalf * 32);
            dl[0] = make_uint4(lw[0], lw[1], lw[2], lw[3]);
            dl[1] = make_uint4(lw[4], lw[5], lw[6], lw[7]);
        }
        // ---- stage B: pre-tiled q1 chunk, contiguous 25600 B
        {
            const uint4* src = (const uint4*)(q1t + c * 12800);
            uint4* dst = (uint4*)(smem + LDS_B);
#pragma unroll
            for (int i = 0; i < 7; ++i) {
                int idx = tid + i * 256;
                if (idx < 1600) dst[idx] = src[idx];
            }
        }
        __syncthreads();
        // ---- compute: wave tile 64x160, 4x10 16x16 tiles, hi+lo into same acc
        bf16x8 ahi[4], alo[4];
#pragma unroll
        for (int mt = 0; mt < 4; ++mt) {
            int row = wm * 64 + mt * 16 + l15;
            ahi[mt] = *(const bf16x8*)(smem + LDS_AHI + row * 80 + quad * 16);
            alo[mt] = *(const bf16x8*)(smem + LDS_ALO + row * 80 + quad * 16);
        }
#pragma unroll
        for (int nt = 0; nt < 10; ++nt) {
            int col = wn * 160 + nt * 16 + l15;
            bf16x8 bq = *(const bf16x8*)(smem + LDS_B + col * 80 + quad * 16);
#pragma unroll
            for (int mt = 0; mt < 4; ++mt) {
                acc[mt][nt] = __builtin_amdgcn_mfma_f32_16x16x32_bf16(ahi[mt], bq, acc[mt][nt], 0, 0, 0);
                acc[mt][nt] = __builtin_amdgcn_mfma_f32_16x16x32_bf16(alo[mt], bq, acc[mt][nt], 0, 0, 0);
            }
        }
    }

    // ---------------- fused epilogue
    __syncthreads();
    // stage q2: tern(w2) -> bf16 [16][328], rows 10..15 and cols 320..327 zero
    for (int idx = tid; idx < 16 * 328; idx += 256) {
        int o = idx / 328, j = idx % 328;
        float v = (o < 10 && j < 320) ? ternf(w2[o * 320 + j]) : 0.0f;
        sm16[(LDS_Q2 >> 1) + idx] = f2bf(v);
    }
    float b1v[10];
#pragma unroll
    for (int nt = 0; nt < 10; ++nt) b1v[nt] = b1[wn * 160 + nt * 16 + l15];
    float b2v = (l15 < 10) ? b2[l15] : 0.0f;

    for (int pass = 0; pass < 2; ++pass) {
        __syncthreads();
        // waves owning this 64-row half write ternarized h (bf16) to LDS
        if (wm == pass) {
#pragma unroll
            for (int mt = 0; mt < 4; ++mt)
#pragma unroll
                for (int nt = 0; nt < 10; ++nt)
#pragma unroll
                    for (int i = 0; i < 4; ++i) {
                        float hv = acc[mt][nt][i] + b1v[nt];
                        int row = mt * 16 + quad * 4 + i;          // C layout: col=lane&15, row=quad*4+reg
                        int col = wn * 160 + nt * 16 + l15;
                        sm16[(LDS_H >> 1) + row * 328 + col] = f2bf(ternf(hv));
                    }
        }
        __syncthreads();
        // layer 2: each wave computes 16 rows x 16 cols (10 valid), K=320
        f32x4 acc2 = {0.f, 0.f, 0.f, 0.f};
#pragma unroll
        for (int kc = 0; kc < 10; ++kc) {
            bf16x8 a = *(const bf16x8*)(smem + LDS_H + (wave * 16 + l15) * 656 + kc * 64 + quad * 16);
            bf16x8 b = *(const bf16x8*)(smem + LDS_Q2 + l15 * 656 + kc * 64 + quad * 16);
            acc2 = __builtin_amdgcn_mfma_f32_16x16x32_bf16(a, b, acc2, 0, 0, 0);
        }
        // log_softmax across the 16 lanes holding one row (cols), 10 valid
#pragma unroll
        for (int i = 0; i < 4; ++i) {
            float l  = acc2[i] + b2v;
            float lm = (l15 < 10) ? l : -3.4e38f;
#pragma unroll
            for (int s = 8; s >= 1; s >>= 1) lm = fmaxf(lm, __shfl_xor(lm, s, 64));
            float e  = (l15 < 10) ? expf(l - lm) : 0.0f;
            float ss = e;
#pragma unroll
            for (int s = 8; s >= 1; s >>= 1) ss += __shfl_xor(ss, s, 64);
            float ov = (l - lm) - logf(ss);
            if (l15 < 10) {
                int grow = blk * 128 + pass * 64 + wave * 16 + quad * 4 + i;
                out[(size_t)grow * 10 + l15] = ov;
            }
        }
    }
}

extern "C" void kernel_launch(void* const* d_in, const int* in_sizes, int n_in,
                              void* d_out, int out_size, void* d_ws, size_t ws_size,
                              hipStream_t stream) {
    const float* x  = (const float*)d_in[0];
    const float* w1 = (const float*)d_in[1];
    const float* b1 = (const float*)d_in[2];
    const float* w2 = (const float*)d_in[3];
    const float* b2 = (const float*)d_in[4];
    unsigned short* q1t = (unsigned short*)d_ws;   // 640000 B

    prep_q1<<<(Q1T_ELEMS + 255) / 256, 256, 0, stream>>>(w1, q1t);
    mlp_main<<<512, 256, 0, stream>>>(x, q1t, b1, w2, b2, (float*)d_out);
}

// Round 3
// 341.818 us; speedup vs baseline: 1.0013x; 1.0013x over previous
//
#include <hip/hip_runtime.h>
#include <stdint.h>

// SmallMLP: x[65536,784] @ tern(w1[320,784])^T + b1 -> tern -> @ tern(w2[10,320])^T + b2 -> log_softmax
// Layer-1 via two-term bf16-split MFMA (16x16x32), fused epilogue (layer 2 + log_softmax).
// R2: register-prefetch software pipeline + conflict-free A staging map.
// R3: fix B-chunk prefetch stride (1600 uint4/chunk, was 800 — silent half-chunk corruption).

#define TERN_TH 0.001f

using bf16x8 = __attribute__((ext_vector_type(8))) short;   // 8 bf16 = 4 VGPR
using f32x4  = __attribute__((ext_vector_type(4))) float;   // 4 fp32 acc

__device__ __forceinline__ unsigned short f2bf(float f) {
    unsigned u = __float_as_uint(f);
    u = (u + 0x7FFFu + ((u >> 16) & 1u)) >> 16;   // RNE
    return (unsigned short)u;
}
__device__ __forceinline__ float bf2f(unsigned short h) {
    return __uint_as_float(((unsigned)h) << 16);
}
__device__ __forceinline__ float ternf(float w) {
    return (w > TERN_TH) ? 1.0f : ((w < -TERN_TH) ? -1.0f : 0.0f);
}

// ---------------- prep: ternarize w1 -> bf16, tiled [25 chunks][320 rows][40 k]
#define Q1T_ELEMS (25 * 320 * 40)
__global__ void prep_q1(const float* __restrict__ w1, unsigned short* __restrict__ q1t) {
    int idx = blockIdx.x * 256 + threadIdx.x;
    if (idx >= Q1T_ELEMS) return;
    int c  = idx / (320 * 40);
    int r  = idx % (320 * 40);
    int j  = r / 40;
    int kk = r % 40;
    int k  = c * 32 + kk;
    float v = 0.0f;
    if (kk < 32 && k < 784) v = ternf(w1[j * 784 + k]);
    q1t[idx] = f2bf(v);
}

// ---------------- LDS layout (bytes)
#define LDS_AHI 0                 // [128][40] bf16 = 10240
#define LDS_ALO 10240             // [128][40] bf16 = 10240
#define LDS_B   20480             // [320][40] bf16 = 25600  -> ends 46080
#define LDS_H   0                 // epilogue: [64][328] bf16 = 41984 (overlaps A/B, dead by then)
#define LDS_Q2  46080             // [16][328] bf16 = 10496  -> total 56576
#define LDS_TOTAL 56576

// B chunk stride: 320 rows * 40 bf16 = 12800 bf16 = 25600 B = 1600 uint4
#define BCHUNK_U4 1600

__global__ __launch_bounds__(256, 2) void mlp_main(
    const float* __restrict__ x, const unsigned short* __restrict__ q1t,
    const float* __restrict__ b1, const float* __restrict__ w2,
    const float* __restrict__ b2, float* __restrict__ out) {

    __shared__ __attribute__((aligned(16))) unsigned char smem[LDS_TOTAL];
    unsigned short* sm16 = (unsigned short*)smem;

    const int tid  = threadIdx.x;
    const int lane = tid & 63;
    const int wave = tid >> 6;     // 4 waves
    const int quad = lane >> 4;
    const int l15  = lane & 15;
    const int wm   = wave >> 1;    // row half (64 rows)
    const int wn   = wave & 1;     // col half (160 cols)
    const int blk  = blockIdx.x;   // 512 blocks * 128 rows

    f32x4 acc[4][10];
#pragma unroll
    for (int mt = 0; mt < 4; ++mt)
#pragma unroll
        for (int nt = 0; nt < 10; ++nt) {
            f32x4 z = {0.f, 0.f, 0.f, 0.f};
            acc[mt][nt] = z;
        }

    // staging coords: conflict-free map — 16-lane phases write 16 consecutive rows
    const int srow  = tid & 127;   // 0..127
    const int shalf = tid >> 7;    // 0..1 (16-float half of the 32-k chunk)
    const float* xrow = x + (size_t)(blk * 128 + srow) * 784 + shalf * 16;
    const uint4* bsrc = (const uint4*)q1t;   // chunk c at + c*BCHUNK_U4

    float4 xr[4];
    uint4  br[7];

    // ---- prologue: load chunk 0
    {
        const float4* s4 = (const float4*)(xrow);
        xr[0] = s4[0]; xr[1] = s4[1]; xr[2] = s4[2]; xr[3] = s4[3];
#pragma unroll
        for (int i = 0; i < 7; ++i) {
            int idx = tid + i * 256;
            br[i] = (idx < BCHUNK_U4) ? bsrc[idx] : make_uint4(0, 0, 0, 0);
        }
    }

    for (int c = 0; c < 25; ++c) {
        __syncthreads();
        // ---- write A: hi/lo bf16 split from prefetched regs
        {
            float v[16];
            v[0]=xr[0].x; v[1]=xr[0].y; v[2]=xr[0].z;  v[3]=xr[0].w;
            v[4]=xr[1].x; v[5]=xr[1].y; v[6]=xr[1].z;  v[7]=xr[1].w;
            v[8]=xr[2].x; v[9]=xr[2].y; v[10]=xr[2].z; v[11]=xr[2].w;
            v[12]=xr[3].x; v[13]=xr[3].y; v[14]=xr[3].z; v[15]=xr[3].w;
            unsigned hw[8], lw[8];
#pragma unroll
            for (int i = 0; i < 8; ++i) {
                unsigned short h0 = f2bf(v[2 * i]);
                unsigned short h1 = f2bf(v[2 * i + 1]);
                unsigned short g0 = f2bf(v[2 * i]     - bf2f(h0));
                unsigned short g1 = f2bf(v[2 * i + 1] - bf2f(h1));
                hw[i] = (unsigned)h0 | ((unsigned)h1 << 16);
                lw[i] = (unsigned)g0 | ((unsigned)g1 << 16);
            }
            uint4* dh = (uint4*)(smem + LDS_AHI + srow * 80 + shalf * 32);
            dh[0] = make_uint4(hw[0], hw[1], hw[2], hw[3]);
            dh[1] = make_uint4(hw[4], hw[5], hw[6], hw[7]);
            uint4* dl = (uint4*)(smem + LDS_ALO + srow * 80 + shalf * 32);
            dl[0] = make_uint4(lw[0], lw[1], lw[2], lw[3]);
            dl[1] = make_uint4(lw[4], lw[5], lw[6], lw[7]);
        }
        // ---- write B from prefetched regs (contiguous: conflict-free)
        {
            uint4* dst = (uint4*)(smem + LDS_B);
#pragma unroll
            for (int i = 0; i < 7; ++i) {
                int idx = tid + i * 256;
                if (idx < BCHUNK_U4) dst[idx] = br[i];
            }
        }
        // ---- prefetch chunk c+1 into regs (stays in flight across barrier & compute)
        if (c < 24) {
            int cn = c + 1;
            if (cn < 24 || shalf == 0) {
                const float4* s4 = (const float4*)(xrow + cn * 32);
                xr[0] = s4[0]; xr[1] = s4[1]; xr[2] = s4[2]; xr[3] = s4[3];
            } else {
                float4 z; z.x = z.y = z.z = z.w = 0.f;   // K tail 784..799
                xr[0] = z; xr[1] = z; xr[2] = z; xr[3] = z;
            }
            const uint4* src = bsrc + (size_t)cn * BCHUNK_U4;
#pragma unroll
            for (int i = 0; i < 7; ++i) {
                int idx = tid + i * 256;
                if (idx < BCHUNK_U4) br[i] = src[idx];
            }
        }
        __syncthreads();
        // ---- compute: wave tile 64x160, 4x10 16x16 tiles, hi+lo into same acc
        bf16x8 ahi[4], alo[4];
#pragma unroll
        for (int mt = 0; mt < 4; ++mt) {
            int row = wm * 64 + mt * 16 + l15;
            ahi[mt] = *(const bf16x8*)(smem + LDS_AHI + row * 80 + quad * 16);
            alo[mt] = *(const bf16x8*)(smem + LDS_ALO + row * 80 + quad * 16);
        }
#pragma unroll
        for (int nt = 0; nt < 10; ++nt) {
            int col = wn * 160 + nt * 16 + l15;
            bf16x8 bq = *(const bf16x8*)(smem + LDS_B + col * 80 + quad * 16);
#pragma unroll
            for (int mt = 0; mt < 4; ++mt) {
                acc[mt][nt] = __builtin_amdgcn_mfma_f32_16x16x32_bf16(ahi[mt], bq, acc[mt][nt], 0, 0, 0);
                acc[mt][nt] = __builtin_amdgcn_mfma_f32_16x16x32_bf16(alo[mt], bq, acc[mt][nt], 0, 0, 0);
            }
        }
    }

    // ---------------- fused epilogue
    __syncthreads();
    // stage q2: tern(w2) -> bf16 [16][328], rows 10..15 and cols 320..327 zero
    for (int idx = tid; idx < 16 * 328; idx += 256) {
        int o = idx / 328, j = idx % 328;
        float v = (o < 10 && j < 320) ? ternf(w2[o * 320 + j]) : 0.0f;
        sm16[(LDS_Q2 >> 1) + idx] = f2bf(v);
    }
    float b1v[10];
#pragma unroll
    for (int nt = 0; nt < 10; ++nt) b1v[nt] = b1[wn * 160 + nt * 16 + l15];
    float b2v = (l15 < 10) ? b2[l15] : 0.0f;

    for (int pass = 0; pass < 2; ++pass) {
        __syncthreads();
        // waves owning this 64-row half write ternarized h (bf16) to LDS
        if (wm == pass) {
#pragma unroll
            for (int mt = 0; mt < 4; ++mt)
#pragma unroll
                for (int nt = 0; nt < 10; ++nt)
#pragma unroll
                    for (int i = 0; i < 4; ++i) {
                        float hv = acc[mt][nt][i] + b1v[nt];
                        int row = mt * 16 + quad * 4 + i;          // C layout: col=lane&15, row=quad*4+reg
                        int col = wn * 160 + nt * 16 + l15;
                        sm16[(LDS_H >> 1) + row * 328 + col] = f2bf(ternf(hv));
                    }
        }
        __syncthreads();
        // layer 2: each wave computes 16 rows x 16 cols (10 valid), K=320
        f32x4 acc2 = {0.f, 0.f, 0.f, 0.f};
#pragma unroll
        for (int kc = 0; kc < 10; ++kc) {
            bf16x8 a = *(const bf16x8*)(smem + LDS_H + (wave * 16 + l15) * 656 + kc * 64 + quad * 16);
            bf16x8 b = *(const bf16x8*)(smem + LDS_Q2 + l15 * 656 + kc * 64 + quad * 16);
            acc2 = __builtin_amdgcn_mfma_f32_16x16x32_bf16(a, b, acc2, 0, 0, 0);
        }
        // log_softmax across the 16 lanes holding one row (cols), 10 valid
#pragma unroll
        for (int i = 0; i < 4; ++i) {
            float l  = acc2[i] + b2v;
            float lm = (l15 < 10) ? l : -3.4e38f;
#pragma unroll
            for (int s = 8; s >= 1; s >>= 1) lm = fmaxf(lm, __shfl_xor(lm, s, 64));
            float e  = (l15 < 10) ? expf(l - lm) : 0.0f;
            float ss = e;
#pragma unroll
            for (int s = 8; s >= 1; s >>= 1) ss += __shfl_xor(ss, s, 64);
            float ov = (l - lm) - logf(ss);
            if (l15 < 10) {
                int grow = blk * 128 + pass * 64 + wave * 16 + quad * 4 + i;
                out[(size_t)grow * 10 + l15] = ov;
            }
        }
    }
}

extern "C" void kernel_launch(void* const* d_in, const int* in_sizes, int n_in,
                              void* d_out, int out_size, void* d_ws, size_t ws_size,
                              hipStream_t stream) {
    const float* x  = (const float*)d_in[0];
    const float* w1 = (const float*)d_in[1];
    const float* b1 = (const float*)d_in[2];
    const float* w2 = (const float*)d_in[3];
    const float* b2 = (const float*)d_in[4];
    unsigned short* q1t = (unsigned short*)d_ws;   // 640000 B

    prep_q1<<<(Q1T_ELEMS + 255) / 256, 256, 0, stream>>>(w1, q1t);
    mlp_main<<<512, 256, 0, stream>>>(x, q1t, b1, w2, b2, (float*)d_out);
}